// Round 2
// baseline (1300.687 us; speedup 1.0000x reference)
//
#include <hip/hip_runtime.h>

// Problem constants (MotionDiscreteAE): B=32, N=2048, D=512, S=2, K=1024, DS=256
#define BN_   65536   // B*N
#define K_    1024
#define DS_   256
#define D_    512
#define TM    64      // m-vectors per block (argmin kernel)
#define TKB   512     // codes per k-tile (argmin kernel)

// global -> LDS async DMA, 16 B per lane; LDS dest = uniform base + lane*16
#define GLDS16(gsrc, ldst)                                              \
  __builtin_amdgcn_global_load_lds(                                     \
      (const __attribute__((address_space(1))) void*)(gsrc),            \
      (__attribute__((address_space(3))) void*)(ldst), 16, 0, 0)

// ---------------------------------------------------------------------------
// Kernel 0: w_sq[s*K + k] = sum_d W[s][k][d]^2  (fp32 chunked; error ~1e-10,
// negligible vs the 1.5e-5 quantization grid of (x_sq + w_sq)).
// ---------------------------------------------------------------------------
__global__ __launch_bounds__(256)
void wsq_kernel(const float* __restrict__ W, float* __restrict__ wsq) {
  const int k = blockIdx.x * 256 + threadIdx.x;  // 0..2047
  const float4* row = (const float4*)(W + (size_t)k * DS_);
  float s0 = 0.f, s1 = 0.f, s2 = 0.f, s3 = 0.f;
#pragma unroll
  for (int i = 0; i < DS_ / 4; ++i) {
    const float4 v = row[i];
    s0 = fmaf(v.x, v.x, s0);
    s1 = fmaf(v.y, v.y, s1);
    s2 = fmaf(v.z, v.z, s2);
    s3 = fmaf(v.w, v.w, s3);
  }
  wsq[k] = (s0 + s1) + (s2 + s3);
}

// ---------------------------------------------------------------------------
// Kernel 0b: xsq[s*BN + m] = np.sum(x*x, -1) BIT-EXACT numpy-pairwise fp32.
// ---------------------------------------------------------------------------
__global__ __launch_bounds__(256)
void xsq_kernel(const float* __restrict__ h, float* __restrict__ xsq) {
  const int idx = blockIdx.x * 256 + threadIdx.x;  // 0..131071
  const int s = idx >> 16;
  const int m = idx & 0xFFFF;
  const float* x = h + (size_t)m * D_ + s * DS_;
  float blk[2];
#pragma unroll
  for (int b = 0; b < 2; ++b) {
    const float* a = x + b * 128;
    float r[8];
#pragma unroll
    for (int j = 0; j < 8; ++j) r[j] = __fmul_rn(a[j], a[j]);
    for (int t = 1; t < 16; ++t) {
#pragma unroll
      for (int j = 0; j < 8; ++j) {
        const float p = __fmul_rn(a[t * 8 + j], a[t * 8 + j]);
        r[j] = __fadd_rn(r[j], p);
      }
    }
    const float s01 = __fadd_rn(r[0], r[1]);
    const float s23 = __fadd_rn(r[2], r[3]);
    const float s45 = __fadd_rn(r[4], r[5]);
    const float s67 = __fadd_rn(r[6], r[7]);
    blk[b] = __fadd_rn(__fadd_rn(s01, s23), __fadd_rn(s45, s67));
  }
  xsq[idx] = __fadd_rn(blk[0], blk[1]);
}

// ---------------------------------------------------------------------------
// Kernel 0c: Wt[s][d][k] = W[s][k][d]  (2 MiB transpose; tiled, coalesced
// both sides). Gives the argmin kernel contiguous [d][k] rows so W-tiles can
// be DMA'd into LDS with global_load_lds (wave-uniform dest + lane*16).
// ---------------------------------------------------------------------------
__global__ __launch_bounds__(256)
void wt_kernel(const float* __restrict__ W, float* __restrict__ Wt) {
  __shared__ float t[32][33];
  const int s  = blockIdx.z;
  const int kb = blockIdx.x * 32;
  const int db = blockIdx.y * 32;
  const int tx = threadIdx.x & 31;
  const int ty = threadIdx.x >> 5;  // 0..7
  const float* Ws  = W  + (size_t)s * K_ * DS_;
  float*       Wts = Wt + (size_t)s * DS_ * K_;
#pragma unroll
  for (int i = 0; i < 4; ++i) {
    const int k = ty + i * 8;  // 0..31
    t[k][tx] = Ws[(size_t)(kb + k) * DS_ + db + tx];
  }
  __syncthreads();
#pragma unroll
  for (int i = 0; i < 4; ++i) {
    const int d = ty + i * 8;  // 0..31
    Wts[(size_t)(db + d) * K_ + kb + tx] = t[tx][d];
  }
}

// ---------------------------------------------------------------------------
// Kernel 1: per (slice s, vector m):
//   argmin_k  D_k = fl32( fl32(xsq_m + wsq_k) - 2*dot(x_m, w_k) )
// Bit-identical distance math to R4 (same 32-d FMA chunk chains, same
// acc += acct chunk-sum order, same strict-< lexicographic argmin).
// R6 (perf only): 8m x 16k register tile (was 4x8) -> 2.7x fewer LDS-read
// instructions per FMA (R4 was LDS-instruction-rate bound: demand 1 b128 /
// 5.3 cyc vs ~1/12 supply -> 47% FMA fraction). W staged via
// global_load_lds DMA from pre-transposed Wt (no ds_writes, no prefetch
// VGPRs); 16 chunks x 2 barriers (was 64 x 2). Per-thread k's spread as
// j*128 + ty*4 + l so every wst b128 read is 8 unique contiguous 16B addrs
// = bank-conflict-free broadcast.
// LDS: xs 64 KiB + wst 64 KiB = 128 KiB -> 1 block/CU (4 waves, 1/SIMD).
// ---------------------------------------------------------------------------
__global__ __launch_bounds__(256, 1)
void argmin_kernel(const float* __restrict__ h, const float* __restrict__ Wt,
                   const float* __restrict__ wsq, const float* __restrict__ xsq,
                   int* __restrict__ ids, float* __restrict__ partials) {
  __shared__ float xs[DS_][TM];    // 64 KiB, [d][m]
  __shared__ float wst[32][TKB];   // 64 KiB, [d][k] current chunk
  // candidate buffers overlay xs (used only after the chunk loop)
  float* candv = &xs[0][0];          // 2048 floats (rows 0..31)
  int*   candi = (int*)&xs[32][0];   // 2048 ints   (rows 32..63)

  const int tid = threadIdx.x;
  const int m0  = blockIdx.x * TM;
  const int s   = blockIdx.y;

  // ---- stage x tile, transposed to [d][m] ----
  {
    const int m  = tid & 63;
    const int dg = tid >> 6;  // 0..3
    const float* xrow = h + (size_t)(m0 + m) * D_ + s * DS_;
#pragma unroll
    for (int it = 0; it < 16; ++it) {
      const int d = it * 16 + dg * 4;
      const float4 v = *(const float4*)(xrow + d);
      xs[d + 0][m] = v.x;
      xs[d + 1][m] = v.y;
      xs[d + 2][m] = v.z;
      xs[d + 3][m] = v.w;
    }
  }
  // first chunk barrier below also covers xs readiness

  const int tx   = tid & 7;   // m-group: m = tx*8 + i
  const int ty   = tid >> 3;  // 0..31; k = kt*512 + j*128 + ty*4 + l
  const int wid  = tid >> 6;  // wave id 0..3
  const int lane = tid & 63;
  const float* __restrict__ wsq_s = wsq + s * K_;
  const float* __restrict__ Wts   = Wt + (size_t)s * DS_ * K_;

  // per-m oracle x_sq (bit-exact numpy value), for this thread's 8 m
  float Xq[8];
#pragma unroll
  for (int i = 0; i < 8; ++i) Xq[i] = xsq[s * BN_ + m0 + tx * 8 + i];

  float bestv[8];
  int   besti[8];
#pragma unroll
  for (int i = 0; i < 8; ++i) { bestv[i] = 3.4e38f; besti[i] = 0x7fffffff; }

  float acc[8][16];
#pragma unroll
  for (int i = 0; i < 8; ++i)
#pragma unroll
    for (int j = 0; j < 16; ++j) acc[i][j] = 0.f;

  // ---- 2 k-tiles x 8 d-chunks of 32 d each ----
#pragma unroll 1
  for (int kt = 0; kt < 2; ++kt) {
#pragma unroll 1
    for (int dc = 0; dc < 8; ++dc) {
      __syncthreads();  // all waves done reading wst for previous chunk
      {                 // DMA this chunk: Wt rows d=dc*32..+31, k=kt*512..+511
        const float* srcb = Wts + ((size_t)dc << 5) * K_ + kt * TKB +
                            (lane << 2);
#pragma unroll
        for (int i2 = 0; i2 < 16; ++i2) {
          const int n = (wid << 4) + i2;  // 0..63, 1 KiB each
          const float* src = srcb + (size_t)(n >> 1) * K_ + ((n & 1) << 8);
          GLDS16(src, &wst[0][0] + (n << 8));
        }
      }
      asm volatile("s_waitcnt vmcnt(0)" ::: "memory");
      __syncthreads();  // wst ready

      // chunk-local accumulator (same rounding order as R4)
      float acct[8][16];
#pragma unroll
      for (int i = 0; i < 8; ++i)
#pragma unroll
        for (int j = 0; j < 16; ++j) acct[i][j] = 0.f;

      const int dbase = dc * 32;
#pragma unroll 2
      for (int d = 0; d < 32; ++d) {
        const float4 a0 = *(const float4*)&xs[dbase + d][tx * 8];
        const float4 a1 = *(const float4*)&xs[dbase + d][tx * 8 + 4];
        const float4 b0 = *(const float4*)&wst[d][ty * 4];
        const float4 b1 = *(const float4*)&wst[d][128 + ty * 4];
        const float4 b2 = *(const float4*)&wst[d][256 + ty * 4];
        const float4 b3 = *(const float4*)&wst[d][384 + ty * 4];
        const float av[8] = {a0.x, a0.y, a0.z, a0.w, a1.x, a1.y, a1.z, a1.w};
        const float bv[16] = {b0.x, b0.y, b0.z, b0.w, b1.x, b1.y, b1.z, b1.w,
                              b2.x, b2.y, b2.z, b2.w, b3.x, b3.y, b3.z, b3.w};
#pragma unroll
        for (int i = 0; i < 8; ++i)
#pragma unroll
          for (int j = 0; j < 16; ++j)
            acct[i][j] = fmaf(av[i], bv[j], acct[i][j]);
      }
#pragma unroll
      for (int i = 0; i < 8; ++i)
#pragma unroll
        for (int j = 0; j < 16; ++j) acc[i][j] += acct[i][j];
    }

    // ---- k-tile complete: fold into per-thread running best ----
    float wq[16];
#pragma unroll
    for (int j = 0; j < 4; ++j)
#pragma unroll
      for (int l = 0; l < 4; ++l)
        wq[j * 4 + l] = wsq_s[kt * TKB + j * 128 + ty * 4 + l];
#pragma unroll
    for (int i = 0; i < 8; ++i) {
#pragma unroll
      for (int j = 0; j < 4; ++j) {
#pragma unroll
        for (int l = 0; l < 4; ++l) {  // (j,l) ascending => thread k ascend
          const int jj = j * 4 + l;
          const int kk = kt * TKB + j * 128 + ty * 4 + l;
          const float t1 = __fadd_rn(Xq[i], wq[jj]);
          const float dv = __fsub_rn(t1, 2.0f * acc[i][jj]);
          if (dv < bestv[i]) { bestv[i] = dv; besti[i] = kk; }
        }
      }
#pragma unroll
      for (int jj = 0; jj < 16; ++jj) acc[i][jj] = 0.f;
    }
  }

  // ---- final merge (once): lexicographic (value, index) == np.argmin ----
  __syncthreads();  // xs free for candidate overlay
#pragma unroll
  for (int i = 0; i < 8; ++i) {
    candv[ty * TM + tx * 8 + i] = bestv[i];
    candi[ty * TM + tx * 8 + i] = besti[i];
  }
  __syncthreads();
  if (tid < TM) {
    float bv = 3.4e38f;
    int   bi = 0x7fffffff;
#pragma unroll
    for (int t = 0; t < 32; ++t) {
      const float v = candv[t * TM + tid];
      const int   c = candi[t * TM + tid];
      if (v < bv || (v == bv && c < bi)) { bv = v; bi = c; }
    }
    ids[s * BN_ + m0 + tid] = bi;
    // VQ-loss partial: bv == quantized ||x - w_best||^2
    float v = bv;
#pragma unroll
    for (int off = 32; off > 0; off >>= 1) v += __shfl_down(v, off);
    if (tid == 0) partials[blockIdx.y * 1024 + blockIdx.x] = v;
  }
}

// ---------------------------------------------------------------------------
// Kernel 2: z[m][d] = W[s][ids[s][m]][d mod 256];  out_ids[m] = id0 + 1024*id1
// ---------------------------------------------------------------------------
__global__ __launch_bounds__(256)
void gather_kernel(const float* __restrict__ W, const int* __restrict__ ids,
                   float* __restrict__ out) {
  const int tid = threadIdx.x;
  float* out_ids = out + (size_t)BN_ * D_;
#pragma unroll
  for (int it = 0; it < 4; ++it) {
    const size_t i4 = (size_t)it * 2097152 + (size_t)blockIdx.x * 256 + tid;
    const size_t e  = i4 * 4;               // element index into [BN, 512]
    const int m  = (int)(e >> 9);
    const int d  = (int)(e & 511);
    const int s  = d >> 8;
    const int dd = d & 255;
    const int id = ids[s * BN_ + m];
    const float4 z = *(const float4*)(W + ((size_t)(s * K_ + id)) * DS_ + dd);
    *(float4*)(out + e) = z;
    if (d == 0) {  // one thread per m writes the packed id (as float value)
      const int id1 = ids[BN_ + m];
      out_ids[m] = (float)(id + (id1 << 10));
    }
  }
}

// ---------------------------------------------------------------------------
// Kernel 3: vq_total = 1.25 * sum(partials) / (BN*DS)
// ---------------------------------------------------------------------------
__global__ __launch_bounds__(256)
void finalize_kernel(const float* __restrict__ partials,
                     float* __restrict__ out_vq) {
  __shared__ float red[256];
  const int tid = threadIdx.x;
  float s = 0.f;
  for (int i = tid; i < 2048; i += 256) s += partials[i];
  red[tid] = s;
  __syncthreads();
  for (int off = 128; off > 0; off >>= 1) {
    if (tid < off) red[tid] += red[tid + off];
    __syncthreads();
  }
  if (tid == 0) out_vq[0] = red[0] * (1.25f / 16777216.f);
}

// ---------------------------------------------------------------------------
extern "C" void kernel_launch(void* const* d_in, const int* in_sizes, int n_in,
                              void* d_out, int out_size, void* d_ws,
                              size_t ws_size, hipStream_t stream) {
  const float* h = (const float*)d_in[0];  // [BN, 512]
  const float* W = (const float*)d_in[1];  // [2, 1024, 256]
  float* out  = (float*)d_out;             // z | ids(as float) | vq_total
  float* wsf  = (float*)d_ws;
  float* wsq      = wsf;                   // 2048 floats
  float* partials = wsf + 2048;            // 2048 floats
  int*   ids      = (int*)(wsf + 4096);    // 131072 ints
  float* xsq      = wsf + 4096 + 131072;   // 131072 floats
  // Wt needs 524288 floats (2 MiB). Prefer workspace; else use the z-region
  // of `out` as scratch (stream-ordered: wt_kernel writes it, argmin reads
  // it, gather_kernel fully overwrites it afterwards).
  const size_t wt_off = 4096 + 131072 + 131072;
  float* Wt = (ws_size >= (wt_off + 524288) * sizeof(float))
                  ? (wsf + wt_off) : out;

  wsq_kernel<<<8, 256, 0, stream>>>(W, wsq);
  xsq_kernel<<<512, 256, 0, stream>>>(h, xsq);
  wt_kernel<<<dim3(32, 8, 2), 256, 0, stream>>>(W, Wt);
  argmin_kernel<<<dim3(1024, 2), 256, 0, stream>>>(h, Wt, wsq, xsq, ids,
                                                   partials);
  gather_kernel<<<8192, 256, 0, stream>>>(W, ids, out);
  finalize_kernel<<<1, 256, 0, stream>>>(partials,
                                         out + (size_t)BN_ * D_ + BN_);
}